// Round 3
// baseline (60.993 us; speedup 1.0000x reference)
//
#include <hip/hip_runtime.h>
#include <math.h>

#define F_SIZE 26
#define F2 676
#define A 5
#define NUM_CLASSES 80
#define T 32
#define NB 128
#define CELLS (F2*A)               // 3380
#define CBLK 14                    // blocks per batch
#define TOTAL_BLOCKS (NB*CBLK)     // 1792
#define CPB 242                    // ceil(3380/14) cells per block
#define FPSCALE 4294967296.0       // 2^32 fixed-point scale

__global__ __launch_bounds__(256) void yolo_one(
    const float* __restrict__ feat,
    const float* __restrict__ box_pred,
    const float* __restrict__ box_conf,
    const float* __restrict__ box_prob,
    const float* __restrict__ targets,
    const float* __restrict__ anchors,
    unsigned long long* __restrict__ acc_cnt,   // [0]=fixed-point sum, [1]=block counter
    float* __restrict__ out)
{
    __shared__ float4 tc[T];
    __shared__ float  ta[T];
    __shared__ float  tcls[T];
    __shared__ float  anc[2*A];
    __shared__ double dred[4];

    const int tid  = threadIdx.x;
    const int b    = blockIdx.x / CBLK;
    const int chunk= blockIdx.x % CBLK;
    const int lane = tid & 63;
    const int wid  = tid >> 6;

    if (tid < T) {
        const float* tg = targets + ((size_t)b*T + tid)*5;
        float x1 = tg[0], y1 = tg[1], x2 = tg[2], y2 = tg[3];
        tc[tid]   = make_float4(x1, y1, x2, y2);
        ta[tid]   = (x2 - x1) * (y2 - y1);
        tcls[tid] = tg[4];
    }
    if (tid >= 64 && tid < 64 + 2*A) anc[tid - 64] = anchors[tid - 64];
    __syncthreads();

    double acc = 0.0;
    const size_t base = (size_t)b * CELLS;

    // ---------------- background: one thread per cell, contiguous chunk ----------------
    const int i = chunk*CPB + tid;
    if (tid < CPB && i < CELLS) {
        const float4 p = *(const float4*)(box_pred + (base + i)*4);
        float px1 = p.x - p.z*0.5f, px2 = p.x + p.z*0.5f;
        float py1 = p.y - p.w*0.5f, py2 = p.y + p.w*0.5f;
        float parea = p.z * p.w;
        bool covered = false;
        #pragma unroll
        for (int t = 0; t < T; t++) {
            float4 c = tc[t];
            float iw = fminf(px2, c.z) - fmaxf(px1, c.x);
            float ih = fminf(py2, c.w) - fmaxf(py1, c.y);
            iw = fmaxf(iw, 0.0f); ih = fmaxf(ih, 0.0f);
            float inter = iw * ih;
            // best_iou > 0.5  <=>  exists t: 3*inter > parea + tarea
            covered = covered || (3.0f*inter > parea + ta[t]);
        }
        if (!covered) {
            float conf = box_conf[base + i];
            acc = 0.5 * (double)(conf*conf);
        }
    }

    // ---------------- matched: wave `wid` handles target t = chunk + 14*wid ----------------
    const int t = chunk + CBLK*wid;
    if (t < T) {
        const int l = lane & 31;              // lanes 32-63 duplicate 0-31
        const float4 c4 = tc[l];
        float x1 = c4.x, y1 = c4.y, x2 = c4.z, y2 = c4.w;
        float cls = tcls[l];
        float cx = (x1+x2)*(F_SIZE*0.5f), cy = (y1+y2)*(F_SIZE*0.5f);
        float tw = (x2-x1)*(float)F_SIZE,  th = (y2-y1)*(float)F_SIZE;
        float fx = floorf(cx), fy = floorf(cy);
        int pos = (int)(fy*(float)F_SIZE + fx);
        int bp = 0; float bi = -1.0f;
        #pragma unroll
        for (int a2 = 0; a2 < A; a2++) {
            float aw = anc[a2*2+0], ah = anc[a2*2+1];
            float inter = fminf(tw, aw) * fminf(th, ah);
            float iou = inter / (tw*th + aw*ah - inter);
            if (iou > bi) { bi = iou; bp = a2; }   // first-max (argmax)
        }
        float mv0 = cx - fx, mv1 = cy - fy;
        float mv2 = logf(tw / anc[bp*2+0]);
        float mv3 = logf(th / anc[bp*2+1]);

        const int my_pos = __shfl(pos, t);
        const int my_bp  = __shfl(bp,  t);
        // last-wins scatter: a higher-index target with the same (pos,anchor) wins
        bool lose = __ballot((lane < T) && (lane > t) && (pos == my_pos) && (bp == my_bp)) != 0ULL;

        if (!lose) {
            const size_t idx = base + (size_t)(my_pos*A + my_bp);

            // covered-bool for this cell, bit-identical arithmetic to background role
            const float4 p = *(const float4*)(box_pred + idx*4);
            float px1 = p.x - p.z*0.5f, px2 = p.x + p.z*0.5f;
            float py1 = p.y - p.w*0.5f, py2 = p.y + p.w*0.5f;
            float parea = p.z * p.w;
            float iw = fminf(px2, x2) - fmaxf(px1, x1);
            float ih = fminf(py2, y2) - fmaxf(py1, y1);
            iw = fmaxf(iw, 0.0f); ih = fmaxf(ih, 0.0f);
            float inter = iw * ih;
            bool covered = __ballot((lane < T) && (3.0f*inter > parea + ta[l])) != 0ULL;

            float conf = box_conf[idx];
            float df = 5.0f * (conf - 1.0f);
            double m = 0.5 * (double)(df*df);
            if (!covered) m -= 0.5 * (double)(conf*conf);   // compensate background add

            const float4 f = *(const float4*)(feat + idx*4);
            float M0 = __shfl(mv0, t), M1 = __shfl(mv1, t);
            float M2 = __shfl(mv2, t), M3 = __shfl(mv3, t);
            float MC = __shfl(cls, t);
            float s0 = 1.0f/(1.0f + expf(-f.x));
            float s1 = 1.0f/(1.0f + expf(-f.y));
            float d0 = s0  - M0, d1 = s1  - M1;
            float d2 = f.z - M2, d3 = f.w - M3;
            m += 0.5 * (double)(d0*d0 + d1*d1 + d2*d2 + d3*d3);

            // class loss: wave-parallel LSE over 80 logits
            const float* pp = box_prob + idx*(size_t)NUM_CLASSES;
            float v0 = pp[lane];
            float v1 = (lane < 16) ? pp[64 + lane] : -3.0e38f;
            float mxv = fmaxf(v0, v1);
            #pragma unroll
            for (int o = 32; o >= 1; o >>= 1) mxv = fmaxf(mxv, __shfl_xor(mxv, o));
            float se = expf(v0 - mxv) + ((lane < 16) ? expf(v1 - mxv) : 0.0f);
            #pragma unroll
            for (int o = 32; o >= 1; o >>= 1) se += __shfl_xor(se, o);
            float lse = mxv + logf(se);
            float picked = pp[(int)MC];
            m += (double)(lse - picked);

            if (lane == 0) acc += m;   // wave contributes once
        }
    }

    // ---------------- reduction: wave shfl -> 4 doubles -> fixed-point atomic ----------------
    #pragma unroll
    for (int o = 32; o >= 1; o >>= 1) acc += __shfl_down(acc, o);
    if (lane == 0) dred[wid] = acc;
    __syncthreads();
    if (tid == 0) {
        double s = dred[0] + dred[1] + dred[2] + dred[3];
        long long v = __double2ll_rn(s * FPSCALE);
        atomicAdd(&acc_cnt[0], (unsigned long long)v);
        __threadfence();
        unsigned long long old = atomicAdd(&acc_cnt[1], 1ULL);
        if (old == (unsigned long long)(TOTAL_BLOCKS - 1)) {
            unsigned long long tot = atomicAdd(&acc_cnt[0], 0ULL);
            double sum = (double)(long long)tot * (1.0 / FPSCALE);
            out[0] = (float)(sum / (double)NB);
        }
    }
}

extern "C" void kernel_launch(void* const* d_in, const int* in_sizes, int n_in,
                              void* d_out, int out_size, void* d_ws, size_t ws_size,
                              hipStream_t stream) {
    const float* feat     = (const float*)d_in[0];
    const float* box_pred = (const float*)d_in[1];
    const float* box_conf = (const float*)d_in[2];
    const float* box_prob = (const float*)d_in[3];
    const float* targets  = (const float*)d_in[4];
    const float* anchors  = (const float*)d_in[5];
    unsigned long long* acc_cnt = (unsigned long long*)d_ws;
    float* out = (float*)d_out;

    hipMemsetAsync(acc_cnt, 0, 16, stream);   // zero sum + counter (graph-capturable)
    yolo_one<<<TOTAL_BLOCKS, 256, 0, stream>>>(
        feat, box_pred, box_conf, box_prob, targets, anchors, acc_cnt, out);
}

// Round 4
// 18.880 us; speedup vs baseline: 3.2305x; 3.2305x over previous
//
#include <hip/hip_runtime.h>
#include <math.h>

#define F_SIZE 26
#define F2 676
#define A 5
#define NUM_CLASSES 80
#define T 32
#define NB 128
#define CELLS (F2*A)               // 3380
#define CBLK 14                    // blocks per batch
#define TOTAL_BLOCKS (NB*CBLK)     // 1792
#define CPB 242                    // ceil(3380/14) cells per block

__global__ __launch_bounds__(256) void yolo_main(
    const float* __restrict__ feat,
    const float* __restrict__ box_pred,
    const float* __restrict__ box_conf,
    const float* __restrict__ box_prob,
    const float* __restrict__ targets,
    const float* __restrict__ anchors,
    double* __restrict__ partial)
{
    __shared__ float4 tc[T];
    __shared__ float  ta[T];
    __shared__ float  tcls[T];
    __shared__ float  anc[2*A];
    __shared__ double dred[4];

    const int tid  = threadIdx.x;
    const int b    = blockIdx.x / CBLK;
    const int chunk= blockIdx.x % CBLK;
    const int lane = tid & 63;
    const int wid  = tid >> 6;

    // ---- issue per-cell global loads FIRST (latency hides behind targets+barrier) ----
    const int i = chunk*CPB + tid;
    const bool active = (tid < CPB) && (i < CELLS);
    const size_t base = (size_t)b * CELLS;
    float4 p = make_float4(0.f, 0.f, 1.f, 1.f);
    float conf = 0.0f;
    if (active) {
        p    = *(const float4*)(box_pred + (base + i)*4);
        conf = box_conf[base + i];
    }

    // ---- targets + anchors to LDS ----
    if (tid < T) {
        const float* tg = targets + ((size_t)b*T + tid)*5;
        float x1 = tg[0], y1 = tg[1], x2 = tg[2], y2 = tg[3];
        tc[tid]   = make_float4(x1, y1, x2, y2);
        ta[tid]   = (x2 - x1) * (y2 - y1);
        tcls[tid] = tg[4];
    }
    if (tid >= 64 && tid < 64 + 2*A) anc[tid - 64] = anchors[tid - 64];
    __syncthreads();

    double acc = 0.0;

    // ---------------- background: one thread per cell ----------------
    if (active) {
        float px1 = p.x - p.z*0.5f, px2 = p.x + p.z*0.5f;
        float py1 = p.y - p.w*0.5f, py2 = p.y + p.w*0.5f;
        float parea = p.z * p.w;
        bool covered = false;
        #pragma unroll
        for (int t = 0; t < T; t++) {
            float4 c = tc[t];
            float iw = fminf(px2, c.z) - fmaxf(px1, c.x);
            float ih = fminf(py2, c.w) - fmaxf(py1, c.y);
            iw = fmaxf(iw, 0.0f); ih = fmaxf(ih, 0.0f);
            float inter = iw * ih;
            // best_iou > 0.5  <=>  exists t: 3*inter > parea + tarea
            covered = covered || (3.0f*inter > parea + ta[t]);
        }
        if (!covered) acc = 0.5 * (double)(conf*conf);
    }

    // ---------------- matched: wave `wid` handles target t = chunk + 14*wid ----------------
    const int t = chunk + CBLK*wid;
    if (t < T) {
        const int l = lane & 31;              // lanes 32-63 duplicate 0-31
        const float4 c4 = tc[l];
        float x1 = c4.x, y1 = c4.y, x2 = c4.z, y2 = c4.w;
        float cls = tcls[l];
        float cx = (x1+x2)*(F_SIZE*0.5f), cy = (y1+y2)*(F_SIZE*0.5f);
        float tw = (x2-x1)*(float)F_SIZE,  th = (y2-y1)*(float)F_SIZE;
        float fx = floorf(cx), fy = floorf(cy);
        int pos = (int)(fy*(float)F_SIZE + fx);
        int bp = 0; float bi = -1.0f;
        #pragma unroll
        for (int a2 = 0; a2 < A; a2++) {
            float aw = anc[a2*2+0], ah = anc[a2*2+1];
            float inter = fminf(tw, aw) * fminf(th, ah);
            float iou = inter / (tw*th + aw*ah - inter);
            if (iou > bi) { bi = iou; bp = a2; }   // first-max (argmax)
        }
        float mv0 = cx - fx, mv1 = cy - fy;
        float mv2 = logf(tw / anc[bp*2+0]);
        float mv3 = logf(th / anc[bp*2+1]);

        const int my_pos = __shfl(pos, t);
        const int my_bp  = __shfl(bp,  t);
        // last-wins scatter: a higher-index target with the same (pos,anchor) wins
        bool lose = __ballot((lane < T) && (lane > t) && (pos == my_pos) && (bp == my_bp)) != 0ULL;

        if (!lose) {
            const size_t idx = base + (size_t)(my_pos*A + my_bp);

            // covered-bool for this cell, bit-identical arithmetic to background role
            const float4 pm = *(const float4*)(box_pred + idx*4);
            float px1 = pm.x - pm.z*0.5f, px2 = pm.x + pm.z*0.5f;
            float py1 = pm.y - pm.w*0.5f, py2 = pm.y + pm.w*0.5f;
            float parea = pm.z * pm.w;
            float iw = fminf(px2, x2) - fmaxf(px1, x1);
            float ih = fminf(py2, y2) - fmaxf(py1, y1);
            iw = fmaxf(iw, 0.0f); ih = fmaxf(ih, 0.0f);
            float inter = iw * ih;
            bool covered = __ballot((lane < T) && (3.0f*inter > parea + ta[l])) != 0ULL;

            float cf = box_conf[idx];
            float df = 5.0f * (cf - 1.0f);
            double m = 0.5 * (double)(df*df);
            if (!covered) m -= 0.5 * (double)(cf*cf);   // compensate background add

            const float4 f = *(const float4*)(feat + idx*4);
            float M0 = __shfl(mv0, t), M1 = __shfl(mv1, t);
            float M2 = __shfl(mv2, t), M3 = __shfl(mv3, t);
            float MC = __shfl(cls, t);
            float s0 = 1.0f/(1.0f + expf(-f.x));
            float s1 = 1.0f/(1.0f + expf(-f.y));
            float d0 = s0  - M0, d1 = s1  - M1;
            float d2 = f.z - M2, d3 = f.w - M3;
            m += 0.5 * (double)(d0*d0 + d1*d1 + d2*d2 + d3*d3);

            // class loss: wave-parallel LSE over 80 logits
            const float* pp = box_prob + idx*(size_t)NUM_CLASSES;
            float v0 = pp[lane];
            float v1 = (lane < 16) ? pp[64 + lane] : -3.0e38f;
            float mxv = fmaxf(v0, v1);
            #pragma unroll
            for (int o = 32; o >= 1; o >>= 1) mxv = fmaxf(mxv, __shfl_xor(mxv, o));
            float se = expf(v0 - mxv) + ((lane < 16) ? expf(v1 - mxv) : 0.0f);
            #pragma unroll
            for (int o = 32; o >= 1; o >>= 1) se += __shfl_xor(se, o);
            float lse = mxv + logf(se);
            float picked = pp[(int)MC];
            m += (double)(lse - picked);

            if (lane == 0) acc += m;   // wave contributes once
        }
    }

    // ---------------- reduction: wave shfl -> 4 doubles -> plain store ----------------
    #pragma unroll
    for (int o = 32; o >= 1; o >>= 1) acc += __shfl_down(acc, o);
    if (lane == 0) dred[wid] = acc;
    __syncthreads();
    if (tid == 0) partial[blockIdx.x] = dred[0] + dred[1] + dred[2] + dred[3];
}

__global__ __launch_bounds__(256) void yolo_reduce(const double* __restrict__ partial,
                                                   float* __restrict__ out)
{
    __shared__ double dred[4];
    const int tid = threadIdx.x;
    const int lane = tid & 63;
    const int wid  = tid >> 6;
    double a = 0.0;
    #pragma unroll
    for (int k = 0; k < 7; k++) {
        int i = tid + k*256;
        if (i < TOTAL_BLOCKS) a += partial[i];
    }
    #pragma unroll
    for (int o = 32; o >= 1; o >>= 1) a += __shfl_down(a, o);
    if (lane == 0) dred[wid] = a;
    __syncthreads();
    if (tid == 0) {
        double s = dred[0] + dred[1] + dred[2] + dred[3];
        out[0] = (float)(s / (double)NB);
    }
}

extern "C" void kernel_launch(void* const* d_in, const int* in_sizes, int n_in,
                              void* d_out, int out_size, void* d_ws, size_t ws_size,
                              hipStream_t stream) {
    const float* feat     = (const float*)d_in[0];
    const float* box_pred = (const float*)d_in[1];
    const float* box_conf = (const float*)d_in[2];
    const float* box_prob = (const float*)d_in[3];
    const float* targets  = (const float*)d_in[4];
    const float* anchors  = (const float*)d_in[5];
    double* partial = (double*)d_ws;   // TOTAL_BLOCKS doubles, fully overwritten each launch
    float* out = (float*)d_out;

    yolo_main<<<TOTAL_BLOCKS, 256, 0, stream>>>(
        feat, box_pred, box_conf, box_prob, targets, anchors, partial);
    yolo_reduce<<<1, 256, 0, stream>>>(partial, out);
}

// Round 6
// 17.181 us; speedup vs baseline: 3.5500x; 1.0989x over previous
//
#include <hip/hip_runtime.h>
#include <math.h>

#define F_SIZE 26
#define F2 676
#define A 5
#define NUM_CLASSES 80
#define T 32
#define NB 128
#define CELLS (F2*A)            // 3380 = 4 * 845
#define CPB 845                 // cells per block (one quarter-batch)
#define NBLK (NB*4)             // 512 blocks, each fully inside one batch
#define TPB 512

__global__ __launch_bounds__(TPB, 4) void yolo_main(
    const float* __restrict__ feat,
    const float* __restrict__ box_pred,
    const float* __restrict__ box_conf,
    const float* __restrict__ box_prob,
    const float* __restrict__ targets,
    const float* __restrict__ anchors,
    double* __restrict__ partial)
{
    __shared__ float4 tc[T];
    __shared__ float  ta[T];
    __shared__ float  tcls[T];
    __shared__ float  anc[2*A];
    __shared__ double dred[8];

    const int tid  = threadIdx.x;
    const int bid  = blockIdx.x;
    const int b    = bid >> 2;          // batch
    const int q    = bid & 3;           // quarter within batch
    const int lane = tid & 63;
    const int wid  = tid >> 6;

    const size_t base = (size_t)b * CELLS;
    const int i0 = q*CPB + tid;         // always < 3380
    const int i1 = i0 + TPB;
    const bool a1 = (tid < CPB - TPB);  // tid < 333

    // ---- issue per-cell global loads first (hide behind LDS fill + barrier) ----
    float4 p0 = *(const float4*)(box_pred + (base + i0)*4);
    float  c0 = box_conf[base + i0];
    float4 p1 = make_float4(0.f,0.f,1.f,1.f);
    float  c1 = 0.0f;
    if (a1) { p1 = *(const float4*)(box_pred + (base + i1)*4); c1 = box_conf[base + i1]; }

    // ---- targets + anchors to LDS ----
    if (tid < T) {
        const float* tg = targets + ((size_t)b*T + tid)*5;
        float x1 = tg[0], y1 = tg[1], x2 = tg[2], y2 = tg[3];
        tc[tid]   = make_float4(x1, y1, x2, y2);
        ta[tid]   = (x2 - x1) * (y2 - y1);
        tcls[tid] = tg[4];
    }
    if (tid >= 64 && tid < 64 + 2*A) anc[tid - 64] = anchors[tid - 64];
    __syncthreads();

    double acc = 0.0;

    // ---------------- background: covered test, 1-2 cells per thread ----------------
    {
        float px10 = p0.x - p0.z*0.5f, px20 = p0.x + p0.z*0.5f;
        float py10 = p0.y - p0.w*0.5f, py20 = p0.y + p0.w*0.5f;
        float pa0  = p0.z * p0.w;
        float px11 = p1.x - p1.z*0.5f, px21 = p1.x + p1.z*0.5f;
        float py11 = p1.y - p1.w*0.5f, py21 = p1.y + p1.w*0.5f;
        float pa1  = p1.z * p1.w;
        bool cov0 = false, cov1 = false;
        #pragma unroll
        for (int t = 0; t < T; t++) {
            float4 c = tc[t]; float tat = ta[t];
            float iw0 = fminf(px20, c.z) - fmaxf(px10, c.x);
            float ih0 = fminf(py20, c.w) - fmaxf(py10, c.y);
            iw0 = fmaxf(iw0, 0.0f); ih0 = fmaxf(ih0, 0.0f);
            cov0 = cov0 || (3.0f*(iw0*ih0) > pa0 + tat);   // best_iou>0.5 <=> 3*inter>pa+ta
            float iw1 = fminf(px21, c.z) - fmaxf(px11, c.x);
            float ih1 = fminf(py21, c.w) - fmaxf(py11, c.y);
            iw1 = fmaxf(iw1, 0.0f); ih1 = fmaxf(ih1, 0.0f);
            cov1 = cov1 || (3.0f*(iw1*ih1) > pa1 + tat);
        }
        if (!cov0)       acc += 0.5 * (double)(c0*c0);
        if (a1 && !cov1) acc += 0.5 * (double)(c1*c1);
    }

    // ---------------- matched: wave wid owns target t = 8q + wid ----------------
    {
        const int t = q*8 + wid;              // always < 32
        const int l = lane & 31;              // lanes 32-63 duplicate 0-31
        const float4 c4 = tc[l];
        float x1 = c4.x, y1 = c4.y, x2 = c4.z, y2 = c4.w;
        float cx = (x1+x2)*(F_SIZE*0.5f), cy = (y1+y2)*(F_SIZE*0.5f);
        float tw = (x2-x1)*(float)F_SIZE,  th = (y2-y1)*(float)F_SIZE;
        float fx = floorf(cx), fy = floorf(cy);
        int pos = (int)(fy*(float)F_SIZE + fx);
        int bp = 0; float bi = -1.0f;
        #pragma unroll
        for (int a2 = 0; a2 < A; a2++) {
            float aw = anc[a2*2+0], ah = anc[a2*2+1];
            float inter = fminf(tw, aw) * fminf(th, ah);
            float iou = inter / (tw*th + aw*ah - inter);
            if (iou > bi) { bi = iou; bp = a2; }   // first-max (argmax)
        }
        const int my_pos = __shfl(pos, t);
        const int my_bp  = __shfl(bp,  t);
        // last-wins scatter: a higher-index target with the same (pos,anchor) wins
        bool lose = __ballot((lane < T) && (lane > t) && (pos == my_pos) && (bp == my_bp)) != 0ULL;

        if (!lose) {
            const size_t idx = base + (size_t)(my_pos*A + my_bp);

            // covered-bool for this cell, bit-identical arithmetic to background role
            const float4 pm = *(const float4*)(box_pred + idx*4);
            float px1 = pm.x - pm.z*0.5f, px2 = pm.x + pm.z*0.5f;
            float py1 = pm.y - pm.w*0.5f, py2 = pm.y + pm.w*0.5f;
            float parea = pm.z * pm.w;
            float iw = fminf(px2, x2) - fmaxf(px1, x1);
            float ih = fminf(py2, y2) - fmaxf(py1, y1);
            iw = fmaxf(iw, 0.0f); ih = fmaxf(ih, 0.0f);
            bool covered = __ballot((lane < T) && (3.0f*(iw*ih) > parea + ta[l])) != 0ULL;

            float cf = box_conf[idx];
            float df = 5.0f * (cf - 1.0f);
            double m = 0.5 * (double)(df*df);
            if (!covered) m -= 0.5 * (double)(cf*cf);   // compensate background add

            float mv0 = cx - fx, mv1 = cy - fy;
            float mv2 = logf(tw / anc[bp*2+0]);
            float mv3 = logf(th / anc[bp*2+1]);
            float M0 = __shfl(mv0, t), M1 = __shfl(mv1, t);
            float M2 = __shfl(mv2, t), M3 = __shfl(mv3, t);
            float MC = __shfl(tcls[l], t);

            const float4 f = *(const float4*)(feat + idx*4);
            float s0 = 1.0f/(1.0f + expf(-f.x));
            float s1 = 1.0f/(1.0f + expf(-f.y));
            float d0 = s0  - M0, d1 = s1  - M1;
            float d2 = f.z - M2, d3 = f.w - M3;
            m += 0.5 * (double)(d0*d0 + d1*d1 + d2*d2 + d3*d3);

            // class loss: wave-parallel LSE over 80 logits
            const float* pp = box_prob + idx*(size_t)NUM_CLASSES;
            float v0 = pp[lane];
            float v1 = (lane < 16) ? pp[64 + lane] : -3.0e38f;
            float mxv = fmaxf(v0, v1);
            #pragma unroll
            for (int o = 32; o >= 1; o >>= 1) mxv = fmaxf(mxv, __shfl_xor(mxv, o));
            float se = expf(v0 - mxv) + ((lane < 16) ? expf(v1 - mxv) : 0.0f);
            #pragma unroll
            for (int o = 32; o >= 1; o >>= 1) se += __shfl_xor(se, o);
            float lse = mxv + logf(se);
            float picked = pp[(int)MC];
            m += (double)(lse - picked);

            if (lane == 0) acc += m;   // wave contributes once
        }
    }

    // ---------------- reduction: wave shfl -> 8 doubles -> plain store ----------------
    #pragma unroll
    for (int o = 32; o >= 1; o >>= 1) acc += __shfl_down(acc, o);
    if (lane == 0) dred[wid] = acc;
    __syncthreads();
    if (tid == 0) {
        double v = 0.0;
        #pragma unroll
        for (int w = 0; w < 8; w++) v += dred[w];
        partial[bid] = v;
    }
}

__global__ __launch_bounds__(TPB) void yolo_reduce(const double* __restrict__ partial,
                                                   float* __restrict__ out)
{
    __shared__ double dred[8];
    const int tid  = threadIdx.x;
    const int lane = tid & 63;
    const int wid  = tid >> 6;
    double a = partial[tid];            // 512 partials, 512 threads
    #pragma unroll
    for (int o = 32; o >= 1; o >>= 1) a += __shfl_down(a, o);
    if (lane == 0) dred[wid] = a;
    __syncthreads();
    if (tid == 0) {
        double s = 0.0;
        #pragma unroll
        for (int w = 0; w < 8; w++) s += dred[w];
        out[0] = (float)(s / (double)NB);
    }
}

extern "C" void kernel_launch(void* const* d_in, const int* in_sizes, int n_in,
                              void* d_out, int out_size, void* d_ws, size_t ws_size,
                              hipStream_t stream) {
    const float* feat     = (const float*)d_in[0];
    const float* box_pred = (const float*)d_in[1];
    const float* box_conf = (const float*)d_in[2];
    const float* box_prob = (const float*)d_in[3];
    const float* targets  = (const float*)d_in[4];
    const float* anchors  = (const float*)d_in[5];
    double* partial = (double*)d_ws;   // NBLK doubles, fully overwritten each launch
    float* out = (float*)d_out;

    yolo_main<<<NBLK, TPB, 0, stream>>>(
        feat, box_pred, box_conf, box_prob, targets, anchors, partial);
    yolo_reduce<<<1, TPB, 0, stream>>>(partial, out);
}